// Round 15
// baseline (444.494 us; speedup 1.0000x reference)
//
#include <hip/hip_runtime.h>
#include <math.h>
#include <limits.h>

#define DIM 2048
#define NEXP 256
#define TOPK 8
#define BM 16
#define BK 16
#define NTH 256
#define NTILE 128

// np-einsum fp32 replica (LOCKED by R3..R14 passes — do not perturb):
//   4 partial chains per output, chain j takes k ≡ j (mod 4);
//   k in 16-groups ascending, within group chunk order 3,2,1,0;
//   separate mul/add rounding (no fma); hadd tree (l0+l1)+(l2+l3);
//   sigmoid in f64 -> f32; pairwise-8 weight sum; ties -> lower index.
// v_pk_*_f32 = element-wise IEEE f32 (bit-identical, halves issue slots).
// R15: SINGLE-buffer LDS (21.5 KB/block) -> 7 blocks/CU = 28 waves/CU.
// Per-block stage->barrier->compute->barrier serializes, but 7 independent
// barrier domains/CU hide it (each wave needs only ~50% duty to keep VALU
// fed). Lessons: R9/R13 counted-vmcnt loses; R14: broadcast x-reads are
// ~free, w-reads 12cyc -> 4r x 256e is the balanced tile; T5 setprio kept.

typedef float f32x2 __attribute__((ext_vector_type(2)));

__device__ __forceinline__ f32x2 pkmul(f32x2 a, f32x2 b) {
    f32x2 d;
    asm("v_pk_mul_f32 %0, %1, %2" : "=v"(d) : "v"(a), "v"(b));
    return d;
}
__device__ __forceinline__ f32x2 pkadd(f32x2 a, f32x2 b) {
    f32x2 d;
    asm("v_pk_add_f32 %0, %1, %2" : "=v"(d) : "v"(a), "v"(b));
    return d;
}

__device__ __forceinline__ void gload16(const void* gptr, void* lptr) {
    __builtin_amdgcn_global_load_lds(
        (const __attribute__((address_space(1))) unsigned int*)(unsigned long long)gptr,
        (__attribute__((address_space(3))) unsigned int*)(unsigned int)(unsigned long long)lptr,
        16, 0, 0);
}

__global__ __launch_bounds__(NTH) void gate_kernel(
    const float* __restrict__ x, const float* __restrict__ w,
    const float* __restrict__ bias, float* __restrict__ outw,
    float* __restrict__ outi)
{
#pragma clang fp contract(off)
    // wbuf: float idx (c*256 + e)*4 + j  (chunk c=0..3, expert e, j=k%4)
    __shared__ float wbuf[4096];      // 16 KB (reused as sc[16][256] after)
    __shared__ float xbuf[256];       // 1 KB  [row*16 + k]
    __shared__ float cval[16 * 32];   // 2 KB  (4 subs x top-8 per row)
    __shared__ int   cidx[16 * 32];   // 2 KB
    // total 21504 B -> 7 blocks/CU

    const int tid   = threadIdx.x;
    const int elane = tid & 63;              // experts elane + 64*i
    const int r0    = (tid >> 6) * 4;        // 4 rows per wave
    const int gr    = blockIdx.x * BM;

    const char* wbase = (const char*)w + (size_t)tid * (DIM * 4);   // expert row `tid`
    const int xrow = tid >> 2, xq = tid & 3;                        // tid<64 stages x
    const char* xbase = (const char*)x + ((size_t)(gr + xrow) * DIM + xq * 4) * 4;

    auto stage = [&](int kt) {
        const size_t kb = (size_t)kt * 64;   // 16 floats = 64 B per tile
        char* dst = (char*)&wbuf[0] + tid * 16;
        gload16(wbase + kb,      dst);
        gload16(wbase + kb + 16, dst + 4096);
        gload16(wbase + kb + 32, dst + 8192);
        gload16(wbase + kb + 48, dst + 12288);
        if (tid < 64)
            gload16(xbase + kb, (char*)&xbuf[0] + tid * 16);
    };

    // acc[r][i][p]: p=0 -> chains (j0,j1), p=1 -> chains (j2,j3)
    f32x2 acc[4][4][2];
#pragma unroll
    for (int r = 0; r < 4; ++r)
#pragma unroll
        for (int i = 0; i < 4; ++i)
#pragma unroll
            for (int p = 0; p < 2; ++p) acc[r][i][p] = (f32x2){0.0f, 0.0f};

    auto compute = [&]() {
#pragma unroll
        for (int c = 3; c >= 0; --c) {          // reversed chunk order in 16-group
            f32x2 xlo[4], xhi[4];
#pragma unroll
            for (int r = 0; r < 4; ++r) {
                const float4 xv = *(const float4*)&xbuf[(r0 + r) * BK + c * 4];
                xlo[r] = (f32x2){xv.x, xv.y};
                xhi[r] = (f32x2){xv.z, xv.w};
            }
            __builtin_amdgcn_s_setprio(1);
#pragma unroll
            for (int i = 0; i < 4; ++i) {
                const float4 wv = *(const float4*)&wbuf[(c * 256 + elane + 64 * i) * 4];
                const f32x2 wlo = (f32x2){wv.x, wv.y};
                const f32x2 whi = (f32x2){wv.z, wv.w};
#pragma unroll
                for (int r = 0; r < 4; ++r) {
                    acc[r][i][0] = pkadd(acc[r][i][0], pkmul(xlo[r], wlo));
                    acc[r][i][1] = pkadd(acc[r][i][1], pkmul(xhi[r], whi));
                }
            }
            __builtin_amdgcn_s_setprio(0);
        }
    };

    // ---- main loop: single-buffer; occupancy (7 blocks/CU) hides latency ----
    for (int kt = 0; kt < NTILE; ++kt) {
        stage(kt);
        __syncthreads();                 // vmcnt(0): LDS tile ready
        compute();
        __syncthreads();                 // all reads done before overwrite
    }

    // ---- epilogue: hadd tree + f64 sigmoid -> scores in wbuf ----
    float* sc = &wbuf[0];                 // [16][256] = 16 KB (exact fit)
#pragma unroll
    for (int r = 0; r < 4; ++r)
#pragma unroll
        for (int i = 0; i < 4; ++i) {
            const float l01 = acc[r][i][0].x + acc[r][i][0].y;
            const float l23 = acc[r][i][1].x + acc[r][i][1].y;
            const float logit = l01 + l23;
            const double s = 1.0 / (1.0 + exp(-(double)logit));
            sc[(r0 + r) * NEXP + (elane + 64 * i)] = (float)s;
        }
    __syncthreads();

    // ---- per-row top-8: 4 subs/row on first 64 threads (64 experts each) ----
    if (tid < 64) {
        const int row = tid >> 2;
        const int sub = tid & 3;
        float tv[TOPK];
        int   ti[TOPK];
#pragma unroll
        for (int q = 0; q < TOPK; ++q) { tv[q] = -INFINITY; ti[q] = INT_MAX; }
        for (int j = 0; j < 64; ++j) {
            const int e = sub + (j << 2);    // ascending index => stable
            const float v = sc[row * NEXP + e] + bias[e];
            if (v > tv[TOPK - 1]) {
                int p = TOPK - 1;
                while (p > 0 && v > tv[p - 1]) {
                    tv[p] = tv[p - 1]; ti[p] = ti[p - 1]; --p;
                }
                tv[p] = v; ti[p] = e;
            }
        }
#pragma unroll
        for (int q = 0; q < TOPK; ++q) {
            cval[row * 32 + sub * 8 + q] = tv[q];
            cidx[row * 32 + sub * 8 + q] = ti[q];
        }
    }
    __syncthreads();

    // ---- leaders (16 threads) merge 4 sorted lists; ties -> lower index ----
    if (tid < 16) {
        const int row = tid;
        int p[4];
#pragma unroll
        for (int s = 0; s < 4; ++s) p[s] = 0;
        float g[TOPK];
        int   sel[TOPK];
        for (int k = 0; k < TOPK; ++k) {
            float best = -INFINITY;
            int bidx = INT_MAX;
            int bs = 0;
#pragma unroll
            for (int s = 0; s < 4; ++s) {
                if (p[s] < 8) {
                    const float v = cval[row * 32 + s * 8 + p[s]];
                    const int  id = cidx[row * 32 + s * 8 + p[s]];
                    if (v > best || (v == best && id < bidx)) {
                        best = v; bidx = id; bs = s;
                    }
                }
            }
            p[bs]++;
            sel[k] = bidx;
            g[k] = sc[row * NEXP + bidx];    // original score (no bias)
        }
        const float s01 = g[0] + g[1], s23 = g[2] + g[3];
        const float s45 = g[4] + g[5], s67 = g[6] + g[7];
        const float wsum = (s01 + s23) + (s45 + s67);
        const float den = wsum + 1e-20f;
        const size_t orow = (size_t)(gr + row) * TOPK;
#pragma unroll
        for (int k = 0; k < TOPK; ++k) {
            outw[orow + k] = (g[k] / den) * 2.5f;
            outi[orow + k] = (float)sel[k];
        }
    }
}

extern "C" void kernel_launch(void* const* d_in, const int* in_sizes, int n_in,
                              void* d_out, int out_size, void* d_ws, size_t ws_size,
                              hipStream_t stream) {
    const float* x    = (const float*)d_in[0];
    const float* w    = (const float*)d_in[1];
    const float* bias = (const float*)d_in[2];
    float* outw = (float*)d_out;
    const int M = in_sizes[0] / DIM;              // 16384 rows
    float* outi = outw + (size_t)M * TOPK;
    const int grid = M / BM;                      // 1024 blocks
    hipLaunchKernelGGL(gate_kernel, dim3(grid), dim3(NTH), 0, stream,
                       x, w, bias, outw, outi);
}

// Round 16
// 394.263 us; speedup vs baseline: 1.1274x; 1.1274x over previous
//
#include <hip/hip_runtime.h>
#include <math.h>
#include <limits.h>

#define DIM 2048
#define NEXP 256
#define TOPK 8
#define BM 32
#define BK 16
#define NTH 512
#define NTILE 128

// np-einsum fp32 replica (LOCKED by R3..R15 passes — do not perturb):
//   4 partial chains per output, chain j takes k ≡ j (mod 4);
//   k in 16-groups ascending, within group chunk order 3,2,1,0;
//   separate mul/add rounding (no fma); hadd tree (l0+l1)+(l2+l3);
//   sigmoid in f64 -> f32; pairwise-8 weight sum; ties -> lower index.
// Structure = R12 (best 395us): BM32/512t, dbuf, setprio, plain sync.
// R16: (a) union-aliased f32x2 halves of the b128 loads (no repack movs),
// (b) pointer-increment staging (no per-gload 64-bit address adds).
// Lessons: R9/R13 vmcnt rings lose; R15 single-buffer loses; R14 aspect
// swap loses; R13 LDS>40KB kills residency; R7 macro-unroll blows VGPR.

typedef float f32x2 __attribute__((ext_vector_type(2)));

union v4u {
    float4 v;
    f32x2  h[2];
};

__device__ __forceinline__ f32x2 pkmul(f32x2 a, f32x2 b) {
    f32x2 d;
    asm("v_pk_mul_f32 %0, %1, %2" : "=v"(d) : "v"(a), "v"(b));
    return d;
}
__device__ __forceinline__ f32x2 pkadd(f32x2 a, f32x2 b) {
    f32x2 d;
    asm("v_pk_add_f32 %0, %1, %2" : "=v"(d) : "v"(a), "v"(b));
    return d;
}

__device__ __forceinline__ void gload16(const void* gptr, void* lptr) {
    __builtin_amdgcn_global_load_lds(
        (const __attribute__((address_space(1))) unsigned int*)(unsigned long long)gptr,
        (__attribute__((address_space(3))) unsigned int*)(unsigned int)(unsigned long long)lptr,
        16, 0, 0);
}

__global__ __launch_bounds__(NTH) void gate_kernel(
    const float* __restrict__ x, const float* __restrict__ w,
    const float* __restrict__ bias, float* __restrict__ outw,
    float* __restrict__ outi)
{
#pragma clang fp contract(off)
    // wbuf[buf]: float idx (c*256 + e)*4 + j  (chunk c=0..3, expert e, j=k%4)
    __shared__ float wbuf[2][4096];   // 32 KB
    __shared__ float xbuf[2][512];    // 4 KB  [row*16 + k]

    const int tid   = threadIdx.x;
    const int elane = tid & 63;              // experts elane + 64*i
    const int r0    = (tid >> 6) * 4;        // 4 rows per wave, 8 waves = 32 rows
    const int gr    = blockIdx.x * BM;

    // ---- staging: w by (expert, chunk-half), x by first 128 threads ----
    const int we    = tid & 255;             // expert row this thread stages
    const int chalf = tid >> 8;              // 0 -> chunks 0,1 ; 1 -> chunks 2,3
    const char* wsrc = (const char*)w + (size_t)we * (DIM * 4) + chalf * 32;
    const char* xsrc = (const char*)x +
        ((size_t)(gr + (tid >> 2)) * DIM + (tid & 3) * 4) * 4;   // tid<128 stages x

    char* const wd0 = (char*)&wbuf[0][0] + we * 16 + chalf * 8192;
    char* const wd1 = (char*)&wbuf[1][0] + we * 16 + chalf * 8192;
    char* const xd0 = (char*)&xbuf[0][0] + tid * 16;
    char* const xd1 = (char*)&xbuf[1][0] + tid * 16;

    auto stage = [&](int buf) {              // sources pre-advanced per tile
        char* wd = buf ? wd1 : wd0;
        gload16(wsrc,      wd);
        gload16(wsrc + 16, wd + 4096);
        if (tid < 128)
            gload16(xsrc, buf ? xd1 : xd0);
    };

    // acc[r][i][p]: p=0 -> chains (j0,j1), p=1 -> chains (j2,j3)
    f32x2 acc[4][4][2];
#pragma unroll
    for (int r = 0; r < 4; ++r)
#pragma unroll
        for (int i = 0; i < 4; ++i)
#pragma unroll
            for (int p = 0; p < 2; ++p) acc[r][i][p] = (f32x2){0.0f, 0.0f};

    auto compute = [&](int buf) {
#pragma unroll
        for (int c = 3; c >= 0; --c) {          // reversed chunk order in 16-group
            v4u xv[4];
#pragma unroll
            for (int r = 0; r < 4; ++r)
                xv[r].v = *(const float4*)&xbuf[buf][(r0 + r) * BK + c * 4];
            __builtin_amdgcn_s_setprio(1);
#pragma unroll
            for (int i = 0; i < 4; ++i) {
                v4u wv;
                wv.v = *(const float4*)&wbuf[buf][(c * 256 + elane + 64 * i) * 4];
#pragma unroll
                for (int r = 0; r < 4; ++r) {
                    acc[r][i][0] = pkadd(acc[r][i][0], pkmul(xv[r].h[0], wv.h[0]));
                    acc[r][i][1] = pkadd(acc[r][i][1], pkmul(xv[r].h[1], wv.h[1]));
                }
            }
            __builtin_amdgcn_s_setprio(0);
        }
    };

    // ---- main loop: double-buffered global_load_lds pipeline ----
    stage(0);
    wsrc += 64; xsrc += 64;
    __syncthreads();
    for (int kt = 0; kt < NTILE; ++kt) {
        const int buf = kt & 1;
        if (kt + 1 < NTILE) {
            stage(buf ^ 1);
            wsrc += 64; xsrc += 64;
        }
        compute(buf);
        __syncthreads();
    }

    // ---- epilogue: hadd tree + f64 sigmoid -> scores fill ALL of wbuf ----
    float* sc = &wbuf[0][0];                 // [32][256] = 32 KB (exact fit)
#pragma unroll
    for (int r = 0; r < 4; ++r)
#pragma unroll
        for (int i = 0; i < 4; ++i) {
            const float l01 = acc[r][i][0].x + acc[r][i][0].y;
            const float l23 = acc[r][i][1].x + acc[r][i][1].y;
            const float logit = l01 + l23;
            const double s = 1.0 / (1.0 + exp(-(double)logit));
            sc[(r0 + r) * NEXP + (elane + 64 * i)] = (float)s;
        }
    __syncthreads();

    float* cval = &xbuf[0][0];               // [32][16]  (2 subs x top-8)
    int*   cidx = (int*)&xbuf[1][0];         // [32][16]

    // ---- per-row top-8: 2 subs/row on first 64 threads (128 experts each) ----
    if (tid < 64) {
        const int row = tid >> 1;
        const int sub = tid & 1;
        float tv[TOPK];
        int   ti[TOPK];
#pragma unroll
        for (int q = 0; q < TOPK; ++q) { tv[q] = -INFINITY; ti[q] = INT_MAX; }
        for (int j = 0; j < 128; ++j) {
            const int e = sub + (j << 1);    // ascending index => stable
            const float v = sc[row * NEXP + e] + bias[e];
            if (v > tv[TOPK - 1]) {
                int p = TOPK - 1;
                while (p > 0 && v > tv[p - 1]) {
                    tv[p] = tv[p - 1]; ti[p] = ti[p - 1]; --p;
                }
                tv[p] = v; ti[p] = e;
            }
        }
#pragma unroll
        for (int q = 0; q < TOPK; ++q) {
            cval[row * 16 + sub * 8 + q] = tv[q];
            cidx[row * 16 + sub * 8 + q] = ti[q];
        }
    }
    __syncthreads();

    // ---- leaders (32 threads) merge 2 sorted lists; ties -> lower index ----
    if (tid < 32) {
        const int row = tid;
        int p0 = 0, p1 = 0;
        float g[TOPK];
        int   sel[TOPK];
#pragma unroll
        for (int k = 0; k < TOPK; ++k) {
            const float v0 = cval[row * 16 + p0];
            const int   i0 = cidx[row * 16 + p0];
            const float v1 = cval[row * 16 + 8 + p1];
            const int   i1 = cidx[row * 16 + 8 + p1];
            int take0;
            if (v0 > v1) take0 = 1;
            else if (v1 > v0) take0 = 0;
            else take0 = (i0 < i1);
            const int e = take0 ? i0 : i1;
            p0 += take0; p1 += 1 - take0;
            sel[k] = e;
            g[k] = sc[row * NEXP + e];       // original score (no bias)
        }
        const float s01 = g[0] + g[1], s23 = g[2] + g[3];
        const float s45 = g[4] + g[5], s67 = g[6] + g[7];
        const float wsum = (s01 + s23) + (s45 + s67);
        const float den = wsum + 1e-20f;
        const size_t orow = (size_t)(gr + row) * TOPK;
#pragma unroll
        for (int k = 0; k < TOPK; ++k) {
            outw[orow + k] = (g[k] / den) * 2.5f;
            outi[orow + k] = (float)sel[k];
        }
    }
}

extern "C" void kernel_launch(void* const* d_in, const int* in_sizes, int n_in,
                              void* d_out, int out_size, void* d_ws, size_t ws_size,
                              hipStream_t stream) {
    const float* x    = (const float*)d_in[0];
    const float* w    = (const float*)d_in[1];
    const float* bias = (const float*)d_in[2];
    float* outw = (float*)d_out;
    const int M = in_sizes[0] / DIM;              // 16384 rows
    float* outi = outw + (size_t)M * TOPK;
    const int grid = M / BM;                      // 512 blocks
    hipLaunchKernelGGL(gate_kernel, dim3(grid), dim3(NTH), 0, stream,
                       x, w, bias, outw, outi);
}